// Round 1
// baseline (1454.476 us; speedup 1.0000x reference)
//
#include <hip/hip_runtime.h>
#include <stdint.h>

typedef __bf16 bf16;
typedef __bf16 bf16x8 __attribute__((ext_vector_type(8)));
typedef __bf16 bf16x4 __attribute__((ext_vector_type(4)));
typedef __bf16 bf16x2 __attribute__((ext_vector_type(2)));
typedef float f32x4 __attribute__((ext_vector_type(4)));
typedef float f32x2 __attribute__((ext_vector_type(2)));

static __device__ __forceinline__ float bflo(uint32_t u) { return __uint_as_float(u << 16); }
static __device__ __forceinline__ float bfhi(uint32_t u) { return __uint_as_float(u & 0xffff0000u); }

// ---------------- init ----------------

__global__ __launch_bounds__(256) void k_init(int* __restrict__ deg, float* __restrict__ stats,
                                              bf16* __restrict__ p, int* __restrict__ ssrc,
                                              int N, int NP, int Ecap) {
    int i = blockIdx.x * 256 + threadIdx.x;
    if (i < N) deg[i] = 0;
    if (i < 3 * 512) stats[i] = 0.f;
    if (i < Ecap) ssrc[i] = N;  // pad -> zero row
    if (i < 128) {
        int g = i >> 4, c = i & 15;
        p[(size_t)g * NP * 16 + (size_t)N * 16 + c] = (bf16)0.f;
    }
}

__global__ __launch_bounds__(256) void k_cvt_w(const float* __restrict__ wl, const float* __restrict__ wr,
                                               bf16* __restrict__ dst, int n) {
    int i = blockIdx.x * 256 + threadIdx.x;
    if (i >= n) return;
    dst[i] = (bf16)wl[i];
    dst[n + i] = (bf16)wr[i];
}

// ---------------- CSR build (XCD-sharded by dst range) ----------------
// blockIdx&7 -> shard g handling dst in [g*B, g*B+B). Each shard streams all E
// edges (int4); atomics + scatter writes stay in the local XCD L2 slice.

__global__ __launch_bounds__(256) void k_count(const int* __restrict__ dst, int* __restrict__ deg,
                                               int E, int B) {
    int g = blockIdx.x & 7;
    int lo = g * B, hi = lo + B;
    int br = blockIdx.x >> 3;
    int nb = gridDim.x >> 3;
    const int4* d4 = (const int4*)dst;
    int E4 = E >> 2;
    for (int i = br * 256 + threadIdx.x; i < E4; i += nb * 256) {
        int4 d = d4[i];
        if (d.x >= lo && d.x < hi) atomicAdd(&deg[d.x], 1);
        if (d.y >= lo && d.y < hi) atomicAdd(&deg[d.y], 1);
        if (d.z >= lo && d.z < hi) atomicAdd(&deg[d.z], 1);
        if (d.w >= lo && d.w < hi) atomicAdd(&deg[d.w], 1);
    }
}

__global__ __launch_bounds__(256) void k_scan1(const int* __restrict__ deg, int* __restrict__ rowptr,
                                               int* __restrict__ bsum, int N) {
    __shared__ int sh[256];
    int i = blockIdx.x * 256 + threadIdx.x;
    int v = (i < N) ? ((deg[i] + 7) & ~7) : 0;
    sh[threadIdx.x] = v;
    for (int off = 1; off < 256; off <<= 1) {
        __syncthreads();
        int t = (threadIdx.x >= off) ? sh[threadIdx.x - off] : 0;
        __syncthreads();
        sh[threadIdx.x] += t;
    }
    __syncthreads();
    if (i <= N) rowptr[i] = sh[threadIdx.x] - v;
    if (threadIdx.x == 255) bsum[blockIdx.x] = sh[255];
}

__global__ __launch_bounds__(512) void k_scan2(int* __restrict__ bsum, int nb) {
    __shared__ int sh[512];
    int v = (threadIdx.x < nb) ? bsum[threadIdx.x] : 0;
    sh[threadIdx.x] = v;
    for (int off = 1; off < 512; off <<= 1) {
        __syncthreads();
        int t = (threadIdx.x >= off) ? sh[threadIdx.x - off] : 0;
        __syncthreads();
        sh[threadIdx.x] += t;
    }
    __syncthreads();
    if (threadIdx.x < nb) bsum[threadIdx.x] = sh[threadIdx.x] - v;
}

__global__ __launch_bounds__(256) void k_scan3(int* __restrict__ rowptr, const int* __restrict__ bsum,
                                               int* __restrict__ cursor, int N) {
    int i = blockIdx.x * 256 + threadIdx.x;
    if (i <= N) {
        int v = rowptr[i] + bsum[i >> 8];
        rowptr[i] = v;
        if (i < N) cursor[i] = v;
    }
}

__global__ __launch_bounds__(256) void k_scatter(const int* __restrict__ src, const int* __restrict__ dst,
                                                 int* __restrict__ cursor, int* __restrict__ ssrc,
                                                 int E, int B) {
    int g = blockIdx.x & 7;
    int lo = g * B, hi = lo + B;
    int br = blockIdx.x >> 3;
    int nb = gridDim.x >> 3;
    const int4* d4 = (const int4*)dst;
    int E4 = E >> 2;
    for (int i = br * 256 + threadIdx.x; i < E4; i += nb * 256) {
        int4 d = d4[i];
        int e = i * 4;
        if (d.x >= lo && d.x < hi) { int pos = atomicAdd(&cursor[d.x], 1); ssrc[pos] = src[e]; }
        if (d.y >= lo && d.y < hi) { int pos = atomicAdd(&cursor[d.y], 1); ssrc[pos] = src[e + 1]; }
        if (d.z >= lo && d.z < hi) { int pos = atomicAdd(&cursor[d.z], 1); ssrc[pos] = src[e + 2]; }
        if (d.w >= lo && d.w < hi) { int pos = atomicAdd(&cursor[d.w], 1); ssrc[pos] = src[e + 3]; }
    }
}

// ---------------- fused GEMM ----------------
// MODE 0: A = x (f32 row-major). MODE 1: A = relu(o*cA+cB), o bf16 col-tiled.
// Out: P_t[g][NP][16] bf16, R_t[g][N][16] bf16 (= X@Wr^T + bl).

template <int MODE>
__global__ __launch_bounds__(256) void k_gemm(const void* __restrict__ srcv, const float* __restrict__ cA,
                                              const float* __restrict__ cB, const bf16* __restrict__ W,
                                              const float* __restrict__ bl, bf16* __restrict__ P,
                                              bf16* __restrict__ R, int Cout, int N, int NP) {
    int wv = blockIdx.x * 4 + (threadIdx.x >> 6);
    int lane = threadIdx.x & 63;
    int node0 = wv * 16;
    if (node0 >= N) return;
    int m = lane & 15, quad = lane >> 4;
    bf16x8 a[4];
    if (MODE == 0) {
        const float* x = (const float*)srcv;
        const float* xr = x + (size_t)(node0 + m) * 128 + quad * 8;
#pragma unroll
        for (int t = 0; t < 4; t++) {
            float4 v0 = *(const float4*)(xr + t * 32);
            float4 v1 = *(const float4*)(xr + t * 32 + 4);
            bf16x8 f = {(bf16)v0.x, (bf16)v0.y, (bf16)v0.z, (bf16)v0.w,
                        (bf16)v1.x, (bf16)v1.y, (bf16)v1.z, (bf16)v1.w};
            a[t] = f;
        }
    } else {
        const bf16* o = (const bf16*)srcv;
#pragma unroll
        for (int t = 0; t < 4; t++) {
            int col0 = t * 32 + quad * 8;
            int g = col0 >> 4;
            int offs = col0 & 15;
            bf16x8 u = *(const bf16x8*)(o + (size_t)g * N * 16 + (size_t)(node0 + m) * 16 + offs);
            float4 ca0 = *(const float4*)(cA + col0);
            float4 ca1 = *(const float4*)(cA + col0 + 4);
            float4 cb0 = *(const float4*)(cB + col0);
            float4 cb1 = *(const float4*)(cB + col0 + 4);
            float h0 = fmaxf(fmaf((float)u[0], ca0.x, cb0.x), 0.f);
            float h1 = fmaxf(fmaf((float)u[1], ca0.y, cb0.y), 0.f);
            float h2 = fmaxf(fmaf((float)u[2], ca0.z, cb0.z), 0.f);
            float h3 = fmaxf(fmaf((float)u[3], ca0.w, cb0.w), 0.f);
            float h4 = fmaxf(fmaf((float)u[4], ca1.x, cb1.x), 0.f);
            float h5 = fmaxf(fmaf((float)u[5], ca1.y, cb1.y), 0.f);
            float h6 = fmaxf(fmaf((float)u[6], ca1.z, cb1.z), 0.f);
            float h7 = fmaxf(fmaf((float)u[7], ca1.w, cb1.w), 0.f);
            bf16x8 f = {(bf16)h0, (bf16)h1, (bf16)h2, (bf16)h3,
                        (bf16)h4, (bf16)h5, (bf16)h6, (bf16)h7};
            a[t] = f;
        }
    }
    int ntiles = (2 * Cout) >> 4;
    int ntilesP = Cout >> 4;
    for (int ct = 0; ct < ntiles; ct++) {
        const bf16* wr = W + (size_t)(ct * 16 + m) * 128 + quad * 8;
        f32x4 acc = {0.f, 0.f, 0.f, 0.f};
        acc = __builtin_amdgcn_mfma_f32_16x16x32_bf16(a[0], *(const bf16x8*)(wr), acc, 0, 0, 0);
        acc = __builtin_amdgcn_mfma_f32_16x16x32_bf16(a[1], *(const bf16x8*)(wr + 32), acc, 0, 0, 0);
        acc = __builtin_amdgcn_mfma_f32_16x16x32_bf16(a[2], *(const bf16x8*)(wr + 64), acc, 0, 0, 0);
        acc = __builtin_amdgcn_mfma_f32_16x16x32_bf16(a[3], *(const bf16x8*)(wr + 96), acc, 0, 0, 0);
        if (ct < ntilesP) {
            bf16* pp = P + (size_t)ct * NP * 16 + (size_t)(node0 + quad * 4) * 16 + m;
            pp[0] = (bf16)acc[0];
            pp[16] = (bf16)acc[1];
            pp[32] = (bf16)acc[2];
            pp[48] = (bf16)acc[3];
        } else {
            int gt = ct - ntilesP;
            float bb = bl[gt * 16 + m];
            bf16* rr = R + (size_t)gt * N * 16 + (size_t)(node0 + quad * 4) * 16 + m;
            rr[0] = (bf16)(acc[0] + bb);
            rr[16] = (bf16)(acc[1] + bb);
            rr[32] = (bf16)(acc[2] + bb);
            rr[48] = (bf16)(acc[3] + bb);
        }
    }
}

// ---------------- aggregate (XCD-sharded, 2 lanes x uint4 per node row) ----------------
// Each 32B feature row (16 bf16 channels) is read by 2 lanes as uint4 (16B each).
// 32 nodes per wave per chunk. Neighbor indices loaded as 2x int4 per 8-edge group.
// Accumulation in packed f32x2 (v_pk_add_f32). VGPR ~90 -> (256,4), 16 waves/CU.

static __device__ __forceinline__ void acc16(uint4 u, f32x2& a0, f32x2& a1, f32x2& a2, f32x2& a3) {
    f32x2 f0 = {bflo(u.x), bfhi(u.x)};
    f32x2 f1 = {bflo(u.y), bfhi(u.y)};
    f32x2 f2 = {bflo(u.z), bfhi(u.z)};
    f32x2 f3 = {bflo(u.w), bfhi(u.w)};
    a0 += f0;
    a1 += f1;
    a2 += f2;
    a3 += f3;
}

template <int NG>
__global__ __launch_bounds__(256, 4) void k_agg(const bf16* __restrict__ p, const bf16* __restrict__ r,
                                                const int* __restrict__ rowptr, const int* __restrict__ deg,
                                                const int* __restrict__ ssrc, bf16* __restrict__ o,
                                                float* __restrict__ ssum, float* __restrict__ ssq,
                                                int N, int NP) {
    int g = blockIdx.x & 7;
    int cg = g % NG;
    constexpr int NREP = 8 / NG;
    int rep = g / NG;
    int wvr = ((blockIdx.x >> 3) * NREP + rep) * 4 + (threadIdx.x >> 6);
    int nwv = (gridDim.x >> 3) * NREP * 4;
    int lane = threadIdx.x & 63;
    int sub = lane & 1;   // which 16B half of the 32B row
    int grp = lane >> 1;  // node slot 0..31
    const uint4* pu = (const uint4*)(p + (size_t)cg * NP * 16) + sub;
    const uint4* ru = (const uint4*)(r + (size_t)cg * N * 16) + sub;
    bf16* ot = o + (size_t)cg * N * 16;
    f32x2 s0 = {0.f, 0.f}, s1 = {0.f, 0.f}, s2 = {0.f, 0.f}, s3 = {0.f, 0.f};
    f32x2 q0 = {0.f, 0.f}, q1 = {0.f, 0.f}, q2 = {0.f, 0.f}, q3 = {0.f, 0.f};
    int nchunk = (N + 31) >> 5;
    for (int c = wvr; c < nchunk; c += nwv) {
        int n = c * 32 + grp;
        bool valid = n < N;
        int e = 0, iters = 0, d = 1;
        if (valid) {
            e = rowptr[n];
            iters = (rowptr[n + 1] - e) >> 3;
            d = deg[n];
        }
        f32x2 a0 = {0.f, 0.f}, a1 = {0.f, 0.f}, a2 = {0.f, 0.f}, a3 = {0.f, 0.f};
        auto gather8 = [&](int4 va, int4 vb) {
            uint4 u0 = pu[(size_t)va.x * 2];
            uint4 u1 = pu[(size_t)va.y * 2];
            uint4 u2 = pu[(size_t)va.z * 2];
            uint4 u3 = pu[(size_t)va.w * 2];
            uint4 u4 = pu[(size_t)vb.x * 2];
            uint4 u5 = pu[(size_t)vb.y * 2];
            uint4 u6 = pu[(size_t)vb.z * 2];
            uint4 u7 = pu[(size_t)vb.w * 2];
            acc16(u0, a0, a1, a2, a3);
            acc16(u1, a0, a1, a2, a3);
            acc16(u2, a0, a1, a2, a3);
            acc16(u3, a0, a1, a2, a3);
            acc16(u4, a0, a1, a2, a3);
            acc16(u5, a0, a1, a2, a3);
            acc16(u6, a0, a1, a2, a3);
            acc16(u7, a0, a1, a2, a3);
        };
        if (iters > 0) {
            const int4* sp = (const int4*)(ssrc + e);
            int4 A0 = sp[0], A1 = sp[1];
            for (int t = 1; t < iters; t++) {
                sp += 2;
                int4 B0 = sp[0], B1 = sp[1];
                gather8(A0, A1);
                A0 = B0;
                A1 = B1;
            }
            gather8(A0, A1);
        }
        if (valid) {
            float sc = 1.0f / (float)(d > 0 ? d : 1);
            uint4 rv = ru[(size_t)n * 2];
            f32x2 w0 = {fmaf(a0.x, sc, bflo(rv.x)), fmaf(a0.y, sc, bfhi(rv.x))};
            f32x2 w1 = {fmaf(a1.x, sc, bflo(rv.y)), fmaf(a1.y, sc, bfhi(rv.y))};
            f32x2 w2 = {fmaf(a2.x, sc, bflo(rv.z)), fmaf(a2.y, sc, bfhi(rv.z))};
            f32x2 w3 = {fmaf(a3.x, sc, bflo(rv.w)), fmaf(a3.y, sc, bfhi(rv.w))};
            bf16x8 ov = {(bf16)w0.x, (bf16)w0.y, (bf16)w1.x, (bf16)w1.y,
                         (bf16)w2.x, (bf16)w2.y, (bf16)w3.x, (bf16)w3.y};
            *(bf16x8*)(ot + (size_t)n * 16 + sub * 8) = ov;
            s0 += w0;
            s1 += w1;
            s2 += w2;
            s3 += w3;
            q0 += w0 * w0;
            q1 += w1 * w1;
            q2 += w2 * w2;
            q3 += w3 * w3;
        }
    }
#pragma unroll
    for (int m = 2; m < 64; m <<= 1) {
        s0.x += __shfl_xor(s0.x, m); s0.y += __shfl_xor(s0.y, m);
        s1.x += __shfl_xor(s1.x, m); s1.y += __shfl_xor(s1.y, m);
        s2.x += __shfl_xor(s2.x, m); s2.y += __shfl_xor(s2.y, m);
        s3.x += __shfl_xor(s3.x, m); s3.y += __shfl_xor(s3.y, m);
        q0.x += __shfl_xor(q0.x, m); q0.y += __shfl_xor(q0.y, m);
        q1.x += __shfl_xor(q1.x, m); q1.y += __shfl_xor(q1.y, m);
        q2.x += __shfl_xor(q2.x, m); q2.y += __shfl_xor(q2.y, m);
        q3.x += __shfl_xor(q3.x, m); q3.y += __shfl_xor(q3.y, m);
    }
    if (grp == 0) {
        int c0 = cg * 16 + sub * 8;
        atomicAdd(&ssum[c0 + 0], s0.x);
        atomicAdd(&ssum[c0 + 1], s0.y);
        atomicAdd(&ssum[c0 + 2], s1.x);
        atomicAdd(&ssum[c0 + 3], s1.y);
        atomicAdd(&ssum[c0 + 4], s2.x);
        atomicAdd(&ssum[c0 + 5], s2.y);
        atomicAdd(&ssum[c0 + 6], s3.x);
        atomicAdd(&ssum[c0 + 7], s3.y);
        atomicAdd(&ssq[c0 + 0], q0.x);
        atomicAdd(&ssq[c0 + 1], q0.y);
        atomicAdd(&ssq[c0 + 2], q1.x);
        atomicAdd(&ssq[c0 + 3], q1.y);
        atomicAdd(&ssq[c0 + 4], q2.x);
        atomicAdd(&ssq[c0 + 5], q2.y);
        atomicAdd(&ssq[c0 + 6], q3.x);
        atomicAdd(&ssq[c0 + 7], q3.y);
    }
}

// ---------------- BN finalize + final output ----------------

__global__ __launch_bounds__(128) void k_bn_fin(const float* __restrict__ ssum, const float* __restrict__ ssq,
                                                const float* __restrict__ gamma, const float* __restrict__ beta,
                                                float* __restrict__ cA, float* __restrict__ cB, int Cout, int N) {
    int c = threadIdx.x;
    if (c >= Cout) return;
    float m = ssum[c] / (float)N;
    float var = ssq[c] / (float)N - m * m;
    float a = gamma[c] * rsqrtf(var + 1e-5f);
    cA[c] = a;
    cB[c] = beta[c] - m * a;
}

__global__ __launch_bounds__(256) void k_norm_out(const bf16* __restrict__ o, const float* __restrict__ cA,
                                                  const float* __restrict__ cB, float* __restrict__ out, int N) {
    int i = blockIdx.x * 256 + threadIdx.x;
    if (i >= N * 8) return;
    int n = i >> 3;
    int col0 = (i & 7) * 8;
    int g = col0 >> 4;
    int offs = col0 & 15;
    bf16x8 u = *(const bf16x8*)(o + (size_t)g * N * 16 + (size_t)n * 16 + offs);
    float4 ca0 = *(const float4*)(cA + col0);
    float4 ca1 = *(const float4*)(cA + col0 + 4);
    float4 cb0 = *(const float4*)(cB + col0);
    float4 cb1 = *(const float4*)(cB + col0 + 4);
    float4 w0, w1;
    w0.x = fmaf((float)u[0], ca0.x, cb0.x);
    w0.y = fmaf((float)u[1], ca0.y, cb0.y);
    w0.z = fmaf((float)u[2], ca0.z, cb0.z);
    w0.w = fmaf((float)u[3], ca0.w, cb0.w);
    w1.x = fmaf((float)u[4], ca1.x, cb1.x);
    w1.y = fmaf((float)u[5], ca1.y, cb1.y);
    w1.z = fmaf((float)u[6], ca1.z, cb1.z);
    w1.w = fmaf((float)u[7], ca1.w, cb1.w);
    *(float4*)(out + (size_t)n * 64 + col0) = w0;
    *(float4*)(out + (size_t)n * 64 + col0 + 4) = w1;
}

// ---------------- launch ----------------

static inline int cdiv(int a, int b) { return (a + b - 1) / b; }

extern "C" void kernel_launch(void* const* d_in, const int* in_sizes, int n_in,
                              void* d_out, int out_size, void* d_ws, size_t ws_size,
                              hipStream_t stream) {
    const float* x = (const float*)d_in[0];
    const int* ei = (const int*)d_in[1];
    const float* Wl[3] = {(const float*)d_in[2], (const float*)d_in[7], (const float*)d_in[12]};
    const float* bl[3] = {(const float*)d_in[3], (const float*)d_in[8], (const float*)d_in[13]};
    const float* Wr[3] = {(const float*)d_in[4], (const float*)d_in[9], (const float*)d_in[14]};
    const float* gam[3] = {(const float*)d_in[5], (const float*)d_in[10], (const float*)d_in[15]};
    const float* bet[3] = {(const float*)d_in[6], (const float*)d_in[11], (const float*)d_in[16]};

    const int N = in_sizes[0] / 128;  // 100000
    const int E = in_sizes[1] / 2;    // 1600000
    const int NP = N + 8;
    const int Ecap = E + 7 * ((N + 7) & ~7);
    const int B = (N + 7) / 8;  // dst-range bucket per XCD
    const int Couts[3] = {128, 128, 64};

    char* base = (char*)d_ws;
    size_t off = 0;
    auto alloc = [&](size_t bytes) -> void* {
        void* ptr = base + off;
        off += (bytes + 255) & ~(size_t)255;
        return ptr;
    };
    bf16* p = (bf16*)alloc((size_t)8 * NP * 16 * 2);
    bf16* r = (bf16*)alloc((size_t)N * 128 * 2);
    bf16* o = (bf16*)alloc((size_t)N * 128 * 2);
    bf16* w0 = (bf16*)alloc(2 * 128 * 128 * 2);
    bf16* w1 = (bf16*)alloc(2 * 128 * 128 * 2);
    bf16* w2 = (bf16*)alloc(2 * 64 * 128 * 2);
    float* stats = (float*)alloc(3 * 512 * 4);
    int* rowptr = (int*)alloc((size_t)(N + 1) * 4);
    int* deg = (int*)alloc((size_t)N * 4);
    int* cursor = (int*)alloc((size_t)N * 4);
    int* bsum = (int*)alloc(512 * 4);
    int* ssrc = (int*)alloc((size_t)Ecap * 4);
    bf16* Wc[3] = {w0, w1, w2};

    const int* esrc = ei;
    const int* edst = ei + E;

    k_init<<<cdiv(Ecap, 256), 256, 0, stream>>>(deg, stats, p, ssrc, N, NP, Ecap);
    k_cvt_w<<<cdiv(128 * 128, 256), 256, 0, stream>>>(Wl[0], Wr[0], w0, 128 * 128);
    k_cvt_w<<<cdiv(128 * 128, 256), 256, 0, stream>>>(Wl[1], Wr[1], w1, 128 * 128);
    k_cvt_w<<<cdiv(64 * 128, 256), 256, 0, stream>>>(Wl[2], Wr[2], w2, 64 * 128);

    k_count<<<2048, 256, 0, stream>>>(edst, deg, E, B);
    int nb = cdiv(N + 1, 256);
    k_scan1<<<nb, 256, 0, stream>>>(deg, rowptr, bsum, N);
    k_scan2<<<1, 512, 0, stream>>>(bsum, nb);
    k_scan3<<<nb, 256, 0, stream>>>(rowptr, bsum, cursor, N);
    k_scatter<<<2048, 256, 0, stream>>>(esrc, edst, cursor, ssrc, E, B);

    const int AGG_BLOCKS = 2048;
    const int GEMM_BLOCKS = cdiv(N, 64);
    for (int l = 0; l < 3; l++) {
        int Cout = Couts[l];
        float* ss = stats + l * 512;
        float* sq = ss + 128;
        float* cA = ss + 256;
        float* cB = ss + 384;
        if (l == 0) {
            k_gemm<0><<<GEMM_BLOCKS, 256, 0, stream>>>(x, nullptr, nullptr, Wc[0], bl[0], p, r, Cout, N, NP);
        } else {
            float* pA = stats + (l - 1) * 512 + 256;
            float* pB = stats + (l - 1) * 512 + 384;
            k_gemm<1><<<GEMM_BLOCKS, 256, 0, stream>>>(o, pA, pB, Wc[l], bl[l], p, r, Cout, N, NP);
        }
        if (Cout == 128) {
            k_agg<8><<<AGG_BLOCKS, 256, 0, stream>>>(p, r, rowptr, deg, ssrc, o, ss, sq, N, NP);
        } else {
            k_agg<4><<<AGG_BLOCKS, 256, 0, stream>>>(p, r, rowptr, deg, ssrc, o, ss, sq, N, NP);
        }
        k_bn_fin<<<1, 128, 0, stream>>>(ss, sq, gam[l], bet[l], cA, cB, Cout, N);
        if (l == 2) {
            k_norm_out<<<cdiv(N * 8, 256), 256, 0, stream>>>(o, cA, cB, (float*)d_out, N);
        }
    }
}

// Round 2
// 760.448 us; speedup vs baseline: 1.9127x; 1.9127x over previous
//
#include <hip/hip_runtime.h>
#include <stdint.h>

typedef __bf16 bf16;
typedef __bf16 bf16x8 __attribute__((ext_vector_type(8)));
typedef __bf16 bf16x4 __attribute__((ext_vector_type(4)));
typedef __bf16 bf16x2 __attribute__((ext_vector_type(2)));
typedef float f32x4 __attribute__((ext_vector_type(4)));

static __device__ __forceinline__ float bflo(uint32_t u) { return __uint_as_float(u << 16); }
static __device__ __forceinline__ float bfhi(uint32_t u) { return __uint_as_float(u & 0xffff0000u); }

// ---------------- init ----------------

__global__ __launch_bounds__(256) void k_init(int* __restrict__ deg, float* __restrict__ stats,
                                              bf16* __restrict__ p, int* __restrict__ ssrc,
                                              int N, int NP, int Ecap) {
    int i = blockIdx.x * 256 + threadIdx.x;
    if (i < N) deg[i] = 0;
    if (i < 3 * 512) stats[i] = 0.f;
    if (i < Ecap) ssrc[i] = N;  // pad -> zero row
    if (i < 128) {
        int g = i >> 4, c = i & 15;
        p[(size_t)g * NP * 16 + (size_t)N * 16 + c] = (bf16)0.f;
    }
}

__global__ __launch_bounds__(256) void k_cvt_w(const float* __restrict__ wl, const float* __restrict__ wr,
                                               bf16* __restrict__ dst, int n) {
    int i = blockIdx.x * 256 + threadIdx.x;
    if (i >= n) return;
    dst[i] = (bf16)wl[i];
    dst[n + i] = (bf16)wr[i];
}

// ---------------- CSR build (XCD-sharded by dst range) ----------------
// blockIdx&7 -> shard g handling dst in [g*B, g*B+B). Each shard streams all E
// edges (int4); atomics + scatter writes stay in the local XCD L2 slice.

__global__ __launch_bounds__(256) void k_count(const int* __restrict__ dst, int* __restrict__ deg,
                                               int E, int B) {
    int g = blockIdx.x & 7;
    int lo = g * B, hi = lo + B;
    int br = blockIdx.x >> 3;
    int nb = gridDim.x >> 3;
    const int4* d4 = (const int4*)dst;
    int E4 = E >> 2;
    for (int i = br * 256 + threadIdx.x; i < E4; i += nb * 256) {
        int4 d = d4[i];
        if (d.x >= lo && d.x < hi) atomicAdd(&deg[d.x], 1);
        if (d.y >= lo && d.y < hi) atomicAdd(&deg[d.y], 1);
        if (d.z >= lo && d.z < hi) atomicAdd(&deg[d.z], 1);
        if (d.w >= lo && d.w < hi) atomicAdd(&deg[d.w], 1);
    }
}

__global__ __launch_bounds__(256) void k_scan1(const int* __restrict__ deg, int* __restrict__ rowptr,
                                               int* __restrict__ bsum, int N) {
    __shared__ int sh[256];
    int i = blockIdx.x * 256 + threadIdx.x;
    int v = (i < N) ? ((deg[i] + 7) & ~7) : 0;
    sh[threadIdx.x] = v;
    for (int off = 1; off < 256; off <<= 1) {
        __syncthreads();
        int t = (threadIdx.x >= off) ? sh[threadIdx.x - off] : 0;
        __syncthreads();
        sh[threadIdx.x] += t;
    }
    __syncthreads();
    if (i <= N) rowptr[i] = sh[threadIdx.x] - v;
    if (threadIdx.x == 255) bsum[blockIdx.x] = sh[255];
}

__global__ __launch_bounds__(512) void k_scan2(int* __restrict__ bsum, int nb) {
    __shared__ int sh[512];
    int v = (threadIdx.x < nb) ? bsum[threadIdx.x] : 0;
    sh[threadIdx.x] = v;
    for (int off = 1; off < 512; off <<= 1) {
        __syncthreads();
        int t = (threadIdx.x >= off) ? sh[threadIdx.x - off] : 0;
        __syncthreads();
        sh[threadIdx.x] += t;
    }
    __syncthreads();
    if (threadIdx.x < nb) bsum[threadIdx.x] = sh[threadIdx.x] - v;
}

__global__ __launch_bounds__(256) void k_scan3(int* __restrict__ rowptr, const int* __restrict__ bsum,
                                               int* __restrict__ cursor, int N) {
    int i = blockIdx.x * 256 + threadIdx.x;
    if (i <= N) {
        int v = rowptr[i] + bsum[i >> 8];
        rowptr[i] = v;
        if (i < N) cursor[i] = v;
    }
}

__global__ __launch_bounds__(256) void k_scatter(const int* __restrict__ src, const int* __restrict__ dst,
                                                 int* __restrict__ cursor, int* __restrict__ ssrc,
                                                 int E, int B) {
    int g = blockIdx.x & 7;
    int lo = g * B, hi = lo + B;
    int br = blockIdx.x >> 3;
    int nb = gridDim.x >> 3;
    const int4* d4 = (const int4*)dst;
    int E4 = E >> 2;
    for (int i = br * 256 + threadIdx.x; i < E4; i += nb * 256) {
        int4 d = d4[i];
        int e = i * 4;
        if (d.x >= lo && d.x < hi) { int pos = atomicAdd(&cursor[d.x], 1); ssrc[pos] = src[e]; }
        if (d.y >= lo && d.y < hi) { int pos = atomicAdd(&cursor[d.y], 1); ssrc[pos] = src[e + 1]; }
        if (d.z >= lo && d.z < hi) { int pos = atomicAdd(&cursor[d.z], 1); ssrc[pos] = src[e + 2]; }
        if (d.w >= lo && d.w < hi) { int pos = atomicAdd(&cursor[d.w], 1); ssrc[pos] = src[e + 3]; }
    }
}

// ---------------- fused GEMM ----------------
// MODE 0: A = x (f32 row-major). MODE 1: A = relu(o*cA+cB), o bf16 col-tiled.
// Out: P_t[g][NP][16] bf16, R_t[g][N][16] bf16 (= X@Wr^T + bl).

template <int MODE>
__global__ __launch_bounds__(256) void k_gemm(const void* __restrict__ srcv, const float* __restrict__ cA,
                                              const float* __restrict__ cB, const bf16* __restrict__ W,
                                              const float* __restrict__ bl, bf16* __restrict__ P,
                                              bf16* __restrict__ R, int Cout, int N, int NP) {
    int wv = blockIdx.x * 4 + (threadIdx.x >> 6);
    int lane = threadIdx.x & 63;
    int node0 = wv * 16;
    if (node0 >= N) return;
    int m = lane & 15, quad = lane >> 4;
    bf16x8 a[4];
    if (MODE == 0) {
        const float* x = (const float*)srcv;
        const float* xr = x + (size_t)(node0 + m) * 128 + quad * 8;
#pragma unroll
        for (int t = 0; t < 4; t++) {
            float4 v0 = *(const float4*)(xr + t * 32);
            float4 v1 = *(const float4*)(xr + t * 32 + 4);
            bf16x8 f = {(bf16)v0.x, (bf16)v0.y, (bf16)v0.z, (bf16)v0.w,
                        (bf16)v1.x, (bf16)v1.y, (bf16)v1.z, (bf16)v1.w};
            a[t] = f;
        }
    } else {
        const bf16* o = (const bf16*)srcv;
#pragma unroll
        for (int t = 0; t < 4; t++) {
            int col0 = t * 32 + quad * 8;
            int g = col0 >> 4;
            int offs = col0 & 15;
            bf16x8 u = *(const bf16x8*)(o + (size_t)g * N * 16 + (size_t)(node0 + m) * 16 + offs);
            float4 ca0 = *(const float4*)(cA + col0);
            float4 ca1 = *(const float4*)(cA + col0 + 4);
            float4 cb0 = *(const float4*)(cB + col0);
            float4 cb1 = *(const float4*)(cB + col0 + 4);
            float h0 = fmaxf(fmaf((float)u[0], ca0.x, cb0.x), 0.f);
            float h1 = fmaxf(fmaf((float)u[1], ca0.y, cb0.y), 0.f);
            float h2 = fmaxf(fmaf((float)u[2], ca0.z, cb0.z), 0.f);
            float h3 = fmaxf(fmaf((float)u[3], ca0.w, cb0.w), 0.f);
            float h4 = fmaxf(fmaf((float)u[4], ca1.x, cb1.x), 0.f);
            float h5 = fmaxf(fmaf((float)u[5], ca1.y, cb1.y), 0.f);
            float h6 = fmaxf(fmaf((float)u[6], ca1.z, cb1.z), 0.f);
            float h7 = fmaxf(fmaf((float)u[7], ca1.w, cb1.w), 0.f);
            bf16x8 f = {(bf16)h0, (bf16)h1, (bf16)h2, (bf16)h3,
                        (bf16)h4, (bf16)h5, (bf16)h6, (bf16)h7};
            a[t] = f;
        }
    }
    int ntiles = (2 * Cout) >> 4;
    int ntilesP = Cout >> 4;
    for (int ct = 0; ct < ntiles; ct++) {
        const bf16* wr = W + (size_t)(ct * 16 + m) * 128 + quad * 8;
        f32x4 acc = {0.f, 0.f, 0.f, 0.f};
        acc = __builtin_amdgcn_mfma_f32_16x16x32_bf16(a[0], *(const bf16x8*)(wr), acc, 0, 0, 0);
        acc = __builtin_amdgcn_mfma_f32_16x16x32_bf16(a[1], *(const bf16x8*)(wr + 32), acc, 0, 0, 0);
        acc = __builtin_amdgcn_mfma_f32_16x16x32_bf16(a[2], *(const bf16x8*)(wr + 64), acc, 0, 0, 0);
        acc = __builtin_amdgcn_mfma_f32_16x16x32_bf16(a[3], *(const bf16x8*)(wr + 96), acc, 0, 0, 0);
        if (ct < ntilesP) {
            bf16* pp = P + (size_t)ct * NP * 16 + (size_t)(node0 + quad * 4) * 16 + m;
            pp[0] = (bf16)acc[0];
            pp[16] = (bf16)acc[1];
            pp[32] = (bf16)acc[2];
            pp[48] = (bf16)acc[3];
        } else {
            int gt = ct - ntilesP;
            float bb = bl[gt * 16 + m];
            bf16* rr = R + (size_t)gt * N * 16 + (size_t)(node0 + quad * 4) * 16 + m;
            rr[0] = (bf16)(acc[0] + bb);
            rr[16] = (bf16)(acc[1] + bb);
            rr[32] = (bf16)(acc[2] + bb);
            rr[48] = (bf16)(acc[3] + bb);
        }
    }
}

// ---------------- aggregate (XCD-sharded, node-per-group, 2-deep pipelined gathers) ----------------
// r0 memory shape (8 lanes x dword per 32B row, 8 nodes/wave, <=8 distinct segments per
// gather instruction) + 2-deep software pipeline: gathers for edge-block t are issued one
// loop iteration before their accumulate, and the index load for t+1 is issued alongside,
// so gather latency overlaps the previous block's accumulate. VGPR ~40, still (256,8).

template <int NG>
__global__ __launch_bounds__(256, 8) void k_agg(const bf16* __restrict__ p, const bf16* __restrict__ r,
                                                const int* __restrict__ rowptr, const int* __restrict__ deg,
                                                const int* __restrict__ ssrc, bf16* __restrict__ o,
                                                float* __restrict__ ssum, float* __restrict__ ssq,
                                                int N, int NP) {
    int g = blockIdx.x & 7;
    int cg = g % NG;
    constexpr int NREP = 8 / NG;
    int rep = g / NG;
    int wvr = ((blockIdx.x >> 3) * NREP + rep) * 4 + (threadIdx.x >> 6);
    int nwv = (gridDim.x >> 3) * NREP * 4;
    int lane = threadIdx.x & 63;
    int sub = lane & 7;
    int grp = lane >> 3;
    const uint32_t* pu = (const uint32_t*)(p + (size_t)cg * NP * 16);
    const uint32_t* ru = (const uint32_t*)(r + (size_t)cg * N * 16);
    bf16* ot = o + (size_t)cg * N * 16;
    float s0 = 0.f, s1 = 0.f, q0 = 0.f, q1 = 0.f;
    int nchunk = (N + 7) >> 3;
    for (int c = wvr; c < nchunk; c += nwv) {
        int n = c * 8 + grp;
        bool valid = n < N;
        int e = 0, iters = 0, d = 1;
        if (valid) {
            e = rowptr[n];
            iters = (rowptr[n + 1] - e) >> 3;
            d = deg[n];
        }
        float a0 = 0.f, a1 = 0.f;
        if (iters > 0) {
            const int* sp = ssrc + e;
            // prologue: indices + gathers for block 0 in flight
            int p0 = sp[0], p1 = sp[1], p2 = sp[2], p3 = sp[3];
            int p4 = sp[4], p5 = sp[5], p6 = sp[6], p7 = sp[7];
            uint32_t A0 = pu[(size_t)p0 * 8 + sub];
            uint32_t A1 = pu[(size_t)p1 * 8 + sub];
            uint32_t A2 = pu[(size_t)p2 * 8 + sub];
            uint32_t A3 = pu[(size_t)p3 * 8 + sub];
            uint32_t A4 = pu[(size_t)p4 * 8 + sub];
            uint32_t A5 = pu[(size_t)p5 * 8 + sub];
            uint32_t A6 = pu[(size_t)p6 * 8 + sub];
            uint32_t A7 = pu[(size_t)p7 * 8 + sub];
            if (iters > 1) {
                // indices for block 1 in flight
                sp += 8;
                p0 = sp[0]; p1 = sp[1]; p2 = sp[2]; p3 = sp[3];
                p4 = sp[4]; p5 = sp[5]; p6 = sp[6]; p7 = sp[7];
            }
            for (int t = 1; t < iters; t++) {
                // issue gathers(t) from indices loaded last iteration
                uint32_t B0 = pu[(size_t)p0 * 8 + sub];
                uint32_t B1 = pu[(size_t)p1 * 8 + sub];
                uint32_t B2 = pu[(size_t)p2 * 8 + sub];
                uint32_t B3 = pu[(size_t)p3 * 8 + sub];
                uint32_t B4 = pu[(size_t)p4 * 8 + sub];
                uint32_t B5 = pu[(size_t)p5 * 8 + sub];
                uint32_t B6 = pu[(size_t)p6 * 8 + sub];
                uint32_t B7 = pu[(size_t)p7 * 8 + sub];
                // issue index load for block t+1
                if (t + 1 < iters) {
                    sp += 8;
                    p0 = sp[0]; p1 = sp[1]; p2 = sp[2]; p3 = sp[3];
                    p4 = sp[4]; p5 = sp[5]; p6 = sp[6]; p7 = sp[7];
                }
                // accumulate gathers(t-1), in flight for a full iteration
                a0 += ((bflo(A0) + bflo(A1)) + (bflo(A2) + bflo(A3))) +
                      ((bflo(A4) + bflo(A5)) + (bflo(A6) + bflo(A7)));
                a1 += ((bfhi(A0) + bfhi(A1)) + (bfhi(A2) + bfhi(A3))) +
                      ((bfhi(A4) + bfhi(A5)) + (bfhi(A6) + bfhi(A7)));
                A0 = B0; A1 = B1; A2 = B2; A3 = B3;
                A4 = B4; A5 = B5; A6 = B6; A7 = B7;
            }
            // epilogue: accumulate last in-flight block
            a0 += ((bflo(A0) + bflo(A1)) + (bflo(A2) + bflo(A3))) +
                  ((bflo(A4) + bflo(A5)) + (bflo(A6) + bflo(A7)));
            a1 += ((bfhi(A0) + bfhi(A1)) + (bfhi(A2) + bfhi(A3))) +
                  ((bfhi(A4) + bfhi(A5)) + (bfhi(A6) + bfhi(A7)));
        }
        if (valid) {
            float sc = 1.0f / (float)(d > 0 ? d : 1);
            uint32_t rv = ru[(size_t)n * 8 + sub];
            float o0 = fmaf(a0, sc, bflo(rv));
            float o1 = fmaf(a1, sc, bfhi(rv));
            bf16x2 ov = {(bf16)o0, (bf16)o1};
            *(bf16x2*)(ot + (size_t)n * 16 + sub * 2) = ov;
            s0 += o0;
            s1 += o1;
            q0 += o0 * o0;
            q1 += o1 * o1;
        }
    }
#pragma unroll
    for (int msk = 8; msk < 64; msk <<= 1) {
        s0 += __shfl_xor(s0, msk, 64);
        s1 += __shfl_xor(s1, msk, 64);
        q0 += __shfl_xor(q0, msk, 64);
        q1 += __shfl_xor(q1, msk, 64);
    }
    if (grp == 0) {
        int c = cg * 16 + sub * 2;
        atomicAdd(&ssum[c], s0);
        atomicAdd(&ssum[c + 1], s1);
        atomicAdd(&ssq[c], q0);
        atomicAdd(&ssq[c + 1], q1);
    }
}

// ---------------- BN finalize + final output ----------------

__global__ __launch_bounds__(128) void k_bn_fin(const float* __restrict__ ssum, const float* __restrict__ ssq,
                                                const float* __restrict__ gamma, const float* __restrict__ beta,
                                                float* __restrict__ cA, float* __restrict__ cB, int Cout, int N) {
    int c = threadIdx.x;
    if (c >= Cout) return;
    float m = ssum[c] / (float)N;
    float var = ssq[c] / (float)N - m * m;
    float a = gamma[c] * rsqrtf(var + 1e-5f);
    cA[c] = a;
    cB[c] = beta[c] - m * a;
}

__global__ __launch_bounds__(256) void k_norm_out(const bf16* __restrict__ o, const float* __restrict__ cA,
                                                  const float* __restrict__ cB, float* __restrict__ out, int N) {
    int i = blockIdx.x * 256 + threadIdx.x;
    if (i >= N * 8) return;
    int n = i >> 3;
    int col0 = (i & 7) * 8;
    int g = col0 >> 4;
    int offs = col0 & 15;
    bf16x8 u = *(const bf16x8*)(o + (size_t)g * N * 16 + (size_t)n * 16 + offs);
    float4 ca0 = *(const float4*)(cA + col0);
    float4 ca1 = *(const float4*)(cA + col0 + 4);
    float4 cb0 = *(const float4*)(cB + col0);
    float4 cb1 = *(const float4*)(cB + col0 + 4);
    float4 w0, w1;
    w0.x = fmaf((float)u[0], ca0.x, cb0.x);
    w0.y = fmaf((float)u[1], ca0.y, cb0.y);
    w0.z = fmaf((float)u[2], ca0.z, cb0.z);
    w0.w = fmaf((float)u[3], ca0.w, cb0.w);
    w1.x = fmaf((float)u[4], ca1.x, cb1.x);
    w1.y = fmaf((float)u[5], ca1.y, cb1.y);
    w1.z = fmaf((float)u[6], ca1.z, cb1.z);
    w1.w = fmaf((float)u[7], ca1.w, cb1.w);
    *(float4*)(out + (size_t)n * 64 + col0) = w0;
    *(float4*)(out + (size_t)n * 64 + col0 + 4) = w1;
}

// ---------------- launch ----------------

static inline int cdiv(int a, int b) { return (a + b - 1) / b; }

extern "C" void kernel_launch(void* const* d_in, const int* in_sizes, int n_in,
                              void* d_out, int out_size, void* d_ws, size_t ws_size,
                              hipStream_t stream) {
    const float* x = (const float*)d_in[0];
    const int* ei = (const int*)d_in[1];
    const float* Wl[3] = {(const float*)d_in[2], (const float*)d_in[7], (const float*)d_in[12]};
    const float* bl[3] = {(const float*)d_in[3], (const float*)d_in[8], (const float*)d_in[13]};
    const float* Wr[3] = {(const float*)d_in[4], (const float*)d_in[9], (const float*)d_in[14]};
    const float* gam[3] = {(const float*)d_in[5], (const float*)d_in[10], (const float*)d_in[15]};
    const float* bet[3] = {(const float*)d_in[6], (const float*)d_in[11], (const float*)d_in[16]};

    const int N = in_sizes[0] / 128;  // 100000
    const int E = in_sizes[1] / 2;    // 1600000
    const int NP = N + 8;
    const int Ecap = E + 7 * ((N + 7) & ~7);
    const int B = (N + 7) / 8;  // dst-range bucket per XCD
    const int Couts[3] = {128, 128, 64};

    char* base = (char*)d_ws;
    size_t off = 0;
    auto alloc = [&](size_t bytes) -> void* {
        void* ptr = base + off;
        off += (bytes + 255) & ~(size_t)255;
        return ptr;
    };
    bf16* p = (bf16*)alloc((size_t)8 * NP * 16 * 2);
    bf16* r = (bf16*)alloc((size_t)N * 128 * 2);
    bf16* o = (bf16*)alloc((size_t)N * 128 * 2);
    bf16* w0 = (bf16*)alloc(2 * 128 * 128 * 2);
    bf16* w1 = (bf16*)alloc(2 * 128 * 128 * 2);
    bf16* w2 = (bf16*)alloc(2 * 64 * 128 * 2);
    float* stats = (float*)alloc(3 * 512 * 4);
    int* rowptr = (int*)alloc((size_t)(N + 1) * 4);
    int* deg = (int*)alloc((size_t)N * 4);
    int* cursor = (int*)alloc((size_t)N * 4);
    int* bsum = (int*)alloc(512 * 4);
    int* ssrc = (int*)alloc((size_t)Ecap * 4);
    bf16* Wc[3] = {w0, w1, w2};

    const int* esrc = ei;
    const int* edst = ei + E;

    k_init<<<cdiv(Ecap, 256), 256, 0, stream>>>(deg, stats, p, ssrc, N, NP, Ecap);
    k_cvt_w<<<cdiv(128 * 128, 256), 256, 0, stream>>>(Wl[0], Wr[0], w0, 128 * 128);
    k_cvt_w<<<cdiv(128 * 128, 256), 256, 0, stream>>>(Wl[1], Wr[1], w1, 128 * 128);
    k_cvt_w<<<cdiv(64 * 128, 256), 256, 0, stream>>>(Wl[2], Wr[2], w2, 64 * 128);

    k_count<<<2048, 256, 0, stream>>>(edst, deg, E, B);
    int nb = cdiv(N + 1, 256);
    k_scan1<<<nb, 256, 0, stream>>>(deg, rowptr, bsum, N);
    k_scan2<<<1, 512, 0, stream>>>(bsum, nb);
    k_scan3<<<nb, 256, 0, stream>>>(rowptr, bsum, cursor, N);
    k_scatter<<<2048, 256, 0, stream>>>(esrc, edst, cursor, ssrc, E, B);

    const int AGG_BLOCKS = 2048;
    const int GEMM_BLOCKS = cdiv(N, 64);
    for (int l = 0; l < 3; l++) {
        int Cout = Couts[l];
        float* ss = stats + l * 512;
        float* sq = ss + 128;
        float* cA = ss + 256;
        float* cB = ss + 384;
        if (l == 0) {
            k_gemm<0><<<GEMM_BLOCKS, 256, 0, stream>>>(x, nullptr, nullptr, Wc[0], bl[0], p, r, Cout, N, NP);
        } else {
            float* pA = stats + (l - 1) * 512 + 256;
            float* pB = stats + (l - 1) * 512 + 384;
            k_gemm<1><<<GEMM_BLOCKS, 256, 0, stream>>>(o, pA, pB, Wc[l], bl[l], p, r, Cout, N, NP);
        }
        if (Cout == 128) {
            k_agg<8><<<AGG_BLOCKS, 256, 0, stream>>>(p, r, rowptr, deg, ssrc, o, ss, sq, N, NP);
        } else {
            k_agg<4><<<AGG_BLOCKS, 256, 0, stream>>>(p, r, rowptr, deg, ssrc, o, ss, sq, N, NP);
        }
        k_bn_fin<<<1, 128, 0, stream>>>(ss, sq, gam[l], bet[l], cA, cB, Cout, N);
        if (l == 2) {
            k_norm_out<<<cdiv(N * 8, 256), 256, 0, stream>>>(o, cA, cB, (float*)d_out, N);
        }
    }
}